// Round 19
// baseline (59.711 us; speedup 1.0000x reference)
//
#include <hip/hip_runtime.h>

// out[b] = sum_g exp(-(||x_b||^2+||c_g||^2-2 x_b.c_g)/2) * w[g]
// B=16384, G=8192, D=64 fp32.
// v19 = v18 (single-pass f16 MFMA, B resident in LDS, VMEM/barrier/branch-
// free K-loop) + POLY-EXP2 ON VALU. R10 measured v_exp_f32 at ~24cyc/wave
// effective (serializing); degree-3 minimax 2^f (rel err ~1e-4, ~3e-13
// absmax vs 4.3e-11 headroom) + v_ldexp_f32 = 8 full-rate VALU ops,
// branchless, clamp-free (ldexp saturates n safely). Trans pipe leaves the
// loop. Also: convert_C zeroes out[] (drops the memset dispatch).

typedef __attribute__((ext_vector_type(8))) _Float16 half8v;
typedef __attribute__((ext_vector_type(16))) float f32x16;
typedef unsigned short u16;
typedef unsigned int u32;

#define L2E   1.4426950408889634f
#define NHL2E 0.72134752044448170f   // log2(e)/2
#define GP 16                        // col parts: 512 cols = 16 tiles each

#define MFMA(a,b,c) __builtin_amdgcn_mfma_f32_32x32x16_f16(a,b,c,0,0,0)

__device__ __forceinline__ void gl_lds16(const void* g, void* l){
  __builtin_amdgcn_global_load_lds((const __attribute__((address_space(1))) u32*)g,
                                   (__attribute__((address_space(3))) u32*)l, 16, 0, 0);
}

// ---- one-time: C [G][64] fp32 -> f16 in MFMA fragment order + (cn,w);
// also zeroes out[] (32768 threads >= B). ----
__global__ __launch_bounds__(256)
void convert_C(const float* __restrict__ C, const float* __restrict__ W,
               _Float16* __restrict__ Cf, float2* __restrict__ cw,
               float* __restrict__ out, int G, int B){
  int idx = blockIdx.x*256 + threadIdx.x;
  if (idx < B) out[idx] = 0.f;
  int g = idx >> 2, f = idx & 3;
  if (g >= G) return;
  const float* row = C + (size_t)g*64 + f*16;
  int cg = g >> 5, cl = g & 31;
  float norm = 0.f;
  _Float16 hv[16];
  #pragma unroll
  for (int q=0; q<4; q++){
    float4 v = *(const float4*)(row + q*4);
    float xv[4] = {v.x, v.y, v.z, v.w};
    #pragma unroll
    for (int e=0; e<4; e++){
      float x = xv[e];
      norm = fmaf(x, x, norm);
      hv[q*4+e] = (_Float16)x;       // RNE f32->f16
    }
  }
  norm += __shfl_xor(norm, 1);       // reduce over the 4 f-lanes of this g
  norm += __shfl_xor(norm, 2);
  size_t u = ((size_t)(cg*4 + f)*64 + cl)*8;
  *(half8v*)(Cf + u)       = *(half8v*)hv;        // h=0 (k 0..7)
  *(half8v*)(Cf + u + 256) = *(half8v*)(hv + 8);  // h=1 (k 8..15)
  if (f == 0) cw[g] = make_float2(-NHL2E*norm, W[g]);
}

__global__ __launch_bounds__(256, 2)
void rbf_mfma(const float* __restrict__ X, const _Float16* __restrict__ Cf,
              const float2* __restrict__ cw, float* __restrict__ out){
  __shared__ __align__(16) half8v Bs[16*4*64];   // 16 tiles x 4 frags x 1KB = 64KB
  __shared__ __align__(16) float2 cwsh[512];     // this part's (cn,w), 4KB

  const int tid = threadIdx.x;
  const int l  = tid & 63;
  const int cl = l & 31;
  const int h  = l >> 5;
  const int w  = tid >> 6;
  const int b  = blockIdx.x;
  const int gp = b & 15;
  const int rows0 = (b >> 4) * 256 + w * 64;

  // ---- issue staging first: B part (16 gl_lds/wave) + cw (1/wave) ----
  {
    const char* src = (const char*)Cf + (size_t)(gp*16)*4096 + (size_t)l*16;
    char* dst = (char*)Bs;
    #pragma unroll
    for (int j=0; j<4; ++j){
      const int tt = w*4 + j;
      #pragma unroll
      for (int f=0; f<4; ++f){
        const size_t o = (size_t)(tt*4 + f)*1024;
        gl_lds16(src + o, dst + o);
      }
    }
    gl_lds16((const char*)(cw + gp*512) + (size_t)w*1024 + (size_t)l*16,
             (char*)cwsh + (size_t)w*1024);
  }

  // ---- A: 64 rows (2 rowfrags) f16 in registers + fp32 row norms ----
  half8v af[2][4];
  float xn[2];
  #pragma unroll
  for (int rf=0; rf<2; rf++){
    const float* xr = X + (size_t)(rows0 + rf*32 + cl)*64;
    float s = 0.f;
    #pragma unroll
    for (int f=0; f<4; f++){
      float4 v0 = *(const float4*)(xr + f*16 + h*8);
      float4 v1 = *(const float4*)(xr + f*16 + h*8 + 4);
      float xv[8] = {v0.x,v0.y,v0.z,v0.w,v1.x,v1.y,v1.z,v1.w};
      _Float16 hv[8];
      #pragma unroll
      for (int e=0;e<8;e++){
        float x = xv[e];
        s = fmaf(x, x, s);
        hv[e] = (_Float16)x;
      }
      af[rf][f] = *(half8v*)hv;
    }
    s += __shfl_xor(s, 32);
    xn[rf] = -NHL2E * s;
  }

  asm volatile("s_waitcnt vmcnt(0)" ::: "memory");
  __syncthreads();   // staging complete; loop below is VMEM- and barrier-free

  half8v bf[2];
  bf[0] = Bs[l];                      // (t=0, f=0)

  float racc0[16], racc1[16];
  #pragma unroll
  for (int r=0;r<16;r++){ racc0[r]=0.f; racc1[r]=0.f; }

  f32x16 aE0, aE1, aO0, aO1;
  float2 cwE, cwO;

  // poly exp2 on VALU: e=n+f via magic RNE; 2^f deg-3 minimax; scale by
  // v_ldexp_f32 (safe for any n). 8 full-rate ops, branchless.
  #define EPIX(P, R, CWV, RACC) do {                                        \
    const float e_ = fmaf(P[R], L2E, CWV.x);                                \
    const float t_ = e_ + 12582912.0f;            /* 1.5*2^23 */            \
    const int   n_ = __float_as_int(t_) - 0x4B400000;                       \
    const float f_ = e_ - (t_ - 12582912.0f);                               \
    float p_ = fmaf(f_, 0.0554906f, 0.2402265f);                            \
    p_ = fmaf(f_, p_, 0.6931472f);                                          \
    p_ = fmaf(f_, p_, 1.0f);                                                \
    RACC[R] = fmaf(__builtin_amdgcn_ldexpf(p_, n_), CWV.y, RACC[R]);        \
  } while(0)

  // tile T: 8 MFMA into (C0,C1) from LDS; EPI of prev tile interleaved.
  #define TILE(T, C0, C1, P0, P1, CWC, CWP, DO_EPI) do {                    \
    const int t_ = (T);                                                     \
    CWC = cwsh[t_*32 + cl];                                                 \
    C0 = (f32x16){}; C1 = (f32x16){};                                       \
    _Pragma("unroll")                                                       \
    for (int f=0; f<4; ++f){                                                \
      const int p = f & 1, q = p ^ 1;                                       \
      const int nf = (f + 1) & 3;                                           \
      const int nt = (f == 3) ? ((t_ + 1) & 15) : t_;                       \
      bf[q] = Bs[(nt*4 + nf)*64 + l];                                       \
      C0 = MFMA(af[0][f], bf[p], C0);                                       \
      if (DO_EPI){                                                          \
        EPIX(P0, f*4+0, CWP, racc0); EPIX(P1, f*4+0, CWP, racc1);           \
        EPIX(P0, f*4+1, CWP, racc0); EPIX(P1, f*4+1, CWP, racc1);           \
      }                                                                     \
      C1 = MFMA(af[1][f], bf[p], C1);                                       \
      if (DO_EPI){                                                          \
        EPIX(P0, f*4+2, CWP, racc0); EPIX(P1, f*4+2, CWP, racc1);           \
        EPIX(P0, f*4+3, CWP, racc0); EPIX(P1, f*4+3, CWP, racc1);           \
      }                                                                     \
    }                                                                       \
  } while(0)

  TILE(0, aE0, aE1, aO0, aO1, cwE, cwO, 0);     // prologue: no EPI yet
  #pragma unroll 1
  for (int tp = 0; tp < 7; ++tp){
    TILE(2*tp + 1, aO0, aO1, aE0, aE1, cwO, cwE, 1);
    TILE(2*tp + 2, aE0, aE1, aO0, aO1, cwE, cwO, 1);
  }
  TILE(15, aO0, aO1, aE0, aE1, cwO, cwE, 1);    // EPIs tile 14
  #pragma unroll
  for (int r=0;r<16;++r){                       // final EPI: tile 15
    EPIX(aO0, r, cwO, racc0);
    EPIX(aO1, r, cwO, racc1);
  }
  #undef TILE
  #undef EPIX

  // ---- reduce over 32 col-lanes, fold 2^xn, one atomic per row ----
  #pragma unroll
  for (int rf=0; rf<2; rf++){
    #pragma unroll
    for (int r=0;r<16;r++){
      float v = rf ? racc1[r] : racc0[r];
      v += __shfl_xor(v, 1);
      v += __shfl_xor(v, 2);
      v += __shfl_xor(v, 4);
      v += __shfl_xor(v, 8);
      v += __shfl_xor(v, 16);
      const int rit = (r&3) + 8*(r>>2) + 4*h;
      const float xnv = __shfl(xn[rf], rit);
      if (cl == 0)
        atomicAdd(&out[rows0 + rf*32 + rit], v * __builtin_amdgcn_exp2f(xnv));
    }
  }
}

extern "C" void kernel_launch(void* const* d_in, const int* in_sizes, int n_in,
                              void* d_out, int out_size, void* d_ws, size_t ws_size,
                              hipStream_t stream) {
  const float* X = (const float*)d_in[0];   // [B,64]
  const float* C = (const float*)d_in[1];   // [G,64]
  const float* W = (const float*)d_in[2];   // [G]
  float* out = (float*)d_out;               // [B]
  const int B = in_sizes[0] / 64;
  const int G = in_sizes[2];

  _Float16* Cf = (_Float16*)d_ws;                // 1 MB, fragment-ordered
  float2* cw = (float2*)(Cf + (size_t)G*64);     // 64 KB

  convert_C<<<(G*4)/256, 256, 0, stream>>>(C, W, Cf, cw, out, G, B);
  rbf_mfma<<<(B/256)*GP, 256, 0, stream>>>(X, Cf, cw, out);
}

// Round 20
// 45.393 us; speedup vs baseline: 1.3154x; 1.3154x over previous
//
#include <hip/hip_runtime.h>

// out[b] = sum_g exp(-(||x_b||^2+||c_g||^2-2 x_b.c_g)/2) * w[g]
// B=16384, G=8192, D=64 fp32.
// v20 = v16 kernel VERBATIM (best: 40.9us, absmax 1.455e-11 vs 5.8e-11 thr;
// single-pass f16 MFMA, reg-streamed B, E/O acc interleave, GSPLIT=12,
// (256,3)) + v19's proven convert_C out-zeroing (drops the memset dispatch:
// headline gap was 7.3us with memset node, 0.8us without).
// History: exp on trans (v16) beats poly-on-VALU (v19, +17us); screening
// branches fragment the schedule (v17, +10us); LDS-resident B neutral (v18);
// P/C wave split raced/spilled (v13/v14); SGB corrupts (v11).

typedef __attribute__((ext_vector_type(8))) _Float16 half8v;
typedef __attribute__((ext_vector_type(16))) float f32x16;
typedef unsigned short u16;
typedef unsigned int u32;

#define L2E   1.4426950408889634f
#define NHL2E 0.72134752044448170f   // log2(e)/2
#define GP 12                        // col parts: gp<4 -> 22 tiles, else 21

#define MFMA(a,b,c) __builtin_amdgcn_mfma_f32_32x32x16_f16(a,b,c,0,0,0)

// ---- one-time: C [G][64] fp32 -> f16 in MFMA fragment order + (cn,w);
// also zeroes out[] (32768 threads >= B; replaces the memset dispatch). ----
__global__ __launch_bounds__(256)
void convert_C(const float* __restrict__ C, const float* __restrict__ W,
               _Float16* __restrict__ Cf, float2* __restrict__ cw,
               float* __restrict__ out, int G, int B){
  int idx = blockIdx.x*256 + threadIdx.x;
  if (idx < B) out[idx] = 0.f;
  int g = idx >> 2, f = idx & 3;
  if (g >= G) return;
  const float* row = C + (size_t)g*64 + f*16;
  int cg = g >> 5, cl = g & 31;
  float norm = 0.f;
  _Float16 hv[16];
  #pragma unroll
  for (int q=0; q<4; q++){
    float4 v = *(const float4*)(row + q*4);
    float xv[4] = {v.x, v.y, v.z, v.w};
    #pragma unroll
    for (int e=0; e<4; e++){
      float x = xv[e];
      norm = fmaf(x, x, norm);
      hv[q*4+e] = (_Float16)x;       // RNE f32->f16
    }
  }
  norm += __shfl_xor(norm, 1);       // reduce over the 4 f-lanes of this g
  norm += __shfl_xor(norm, 2);
  size_t u = ((size_t)(cg*4 + f)*64 + cl)*8;
  *(half8v*)(Cf + u)       = *(half8v*)hv;        // h=0 (k 0..7)
  *(half8v*)(Cf + u + 256) = *(half8v*)(hv + 8);  // h=1 (k 8..15)
  if (f == 0) cw[g] = make_float2(-NHL2E*norm, W[g]);
}

__global__ __launch_bounds__(256, 3)
void rbf_mfma(const float* __restrict__ X, const _Float16* __restrict__ Cf,
              const float2* __restrict__ cw, float* __restrict__ out){
  const int tid = threadIdx.x;
  const int l  = tid & 63;
  const int cl = l & 31;
  const int h  = l >> 5;
  const int w  = tid >> 6;
  const int b  = blockIdx.x;
  const int gp = b % GP;               // 4 waves share gp -> L1/L2 B-sharing
  const int rows0 = (b / GP) * 256 + w * 64;

  // global col-tile range for this part (256 tiles of 32 cols over G)
  const int t0  = gp * 21 + (gp < 4 ? gp : 4);
  const int ntl = (gp < 4) ? 22 : 21;

  // ---- A: 64 rows (2 rowfrags) f16 in registers + fp32 row norms ----
  half8v af[2][4];
  float xn[2];
  #pragma unroll
  for (int rf=0; rf<2; rf++){
    const float* xr = X + (size_t)(rows0 + rf*32 + cl)*64;
    float s = 0.f;
    #pragma unroll
    for (int f=0; f<4; f++){
      float4 v0 = *(const float4*)(xr + f*16 + h*8);
      float4 v1 = *(const float4*)(xr + f*16 + h*8 + 4);
      float xv[8] = {v0.x,v0.y,v0.z,v0.w,v1.x,v1.y,v1.z,v1.w};
      _Float16 hv[8];
      #pragma unroll
      for (int e=0;e<8;e++){
        float x = xv[e];
        s = fmaf(x, x, s);
        hv[e] = (_Float16)x;
      }
      af[rf][f] = *(half8v*)hv;
    }
    s += __shfl_xor(s, 32);
    xn[rf] = -NHL2E * s;
  }

  // B stream: byte addr = T*4096 + f*1024 + l*16 (T = global col-tile)
  const char* baseF = (const char*)Cf + (size_t)l*16;
  const float2* cwp = cw + cl;

  half8v bf[2];
  bf[0] = *(const half8v*)(baseF + (size_t)t0*4096);   // (t0, f=0)

  float racc0[16], racc1[16];
  #pragma unroll
  for (int r=0;r<16;r++){ racc0[r]=0.f; racc1[r]=0.f; }

  f32x16 aE0, aE1, aO0, aO1;
  float2 cwE, cwO;

  // one epilogue element: RACC[R] += 2^(L2E*P[R] + CWV.x) * CWV.y
  #define EPIX(P, R, CWV, RACC)                                             \
    RACC[R] = fmaf(__builtin_amdgcn_exp2f(fmaf(P[R], L2E, CWV.x)),          \
                   CWV.y, RACC[R])

  // tile T (runtime), TN = next tile to prefetch toward; 8 MFMA into
  // (C0,C1); EPI of prev tile interleaved 4 per MFMA. Ping-pong parity
  // is static (f&1).
  #define TILE(T, TN, C0, C1, P0, P1, CWC, CWP, DO_EPI) do {                \
    const int t_ = (T), tn_ = (TN);                                         \
    CWC = cwp[t_*32];                                                       \
    C0 = (f32x16){}; C1 = (f32x16){};                                       \
    _Pragma("unroll")                                                       \
    for (int f=0; f<4; ++f){                                                \
      const int p = f & 1, q = p ^ 1;                                       \
      const int nf = (f + 1) & 3;                                           \
      const int nt = (f == 3) ? tn_ : t_;                                   \
      bf[q] = *(const half8v*)(baseF + (size_t)nt*4096 + (size_t)nf*1024);  \
      C0 = MFMA(af[0][f], bf[p], C0);                                       \
      if (DO_EPI){                                                          \
        EPIX(P0, f*4+0, CWP, racc0); EPIX(P1, f*4+0, CWP, racc1);           \
        EPIX(P0, f*4+1, CWP, racc0); EPIX(P1, f*4+1, CWP, racc1);           \
      }                                                                     \
      C1 = MFMA(af[1][f], bf[p], C1);                                       \
      if (DO_EPI){                                                          \
        EPIX(P0, f*4+2, CWP, racc0); EPIX(P1, f*4+2, CWP, racc1);           \
        EPIX(P0, f*4+3, CWP, racc0); EPIX(P1, f*4+3, CWP, racc1);           \
      }                                                                     \
    }                                                                       \
  } while(0)

  // prologue tile (even slot), no EPI
  TILE(t0, t0+1, aE0, aE1, aO0, aO1, cwE, cwO, 0);
  int ti = 1;
  #pragma unroll 1
  for (; ti + 1 < ntl; ti += 2){
    const int To = t0 + ti, Te = t0 + ti + 1;
    const int TnO = Te;                            // next after odd tile
    const int TnE = (ti + 2 < ntl) ? Te + 1 : t0;  // wrap: prefetch unused
    TILE(To, TnO, aO0, aO1, aE0, aE1, cwO, cwE, 1);
    TILE(Te, TnE, aE0, aE1, aO0, aO1, cwE, cwO, 1);
  }
  if (ti < ntl){
    // ntl even: one final odd tile, then flush both
    TILE(t0+ti, t0, aO0, aO1, aE0, aE1, cwO, cwE, 1);
    #pragma unroll
    for (int r=0;r<16;++r){ EPIX(aO0, r, cwO, racc0); EPIX(aO1, r, cwO, racc1); }
  } else {
    // ntl odd: flush the last even tile
    #pragma unroll
    for (int r=0;r<16;++r){ EPIX(aE0, r, cwE, racc0); EPIX(aE1, r, cwE, racc1); }
  }
  #undef TILE
  #undef EPIX

  // ---- reduce over 32 col-lanes, fold 2^xn, one atomic per row ----
  #pragma unroll
  for (int rf=0; rf<2; rf++){
    #pragma unroll
    for (int r=0;r<16;r++){
      float v = rf ? racc1[r] : racc0[r];
      v += __shfl_xor(v, 1);
      v += __shfl_xor(v, 2);
      v += __shfl_xor(v, 4);
      v += __shfl_xor(v, 8);
      v += __shfl_xor(v, 16);
      const int rit = (r&3) + 8*(r>>2) + 4*h;
      const float xnv = __shfl(xn[rf], rit);
      if (cl == 0)
        atomicAdd(&out[rows0 + rf*32 + rit], v * __builtin_amdgcn_exp2f(xnv));
    }
  }
}

extern "C" void kernel_launch(void* const* d_in, const int* in_sizes, int n_in,
                              void* d_out, int out_size, void* d_ws, size_t ws_size,
                              hipStream_t stream) {
  const float* X = (const float*)d_in[0];   // [B,64]
  const float* C = (const float*)d_in[1];   // [G,64]
  const float* W = (const float*)d_in[2];   // [G]
  float* out = (float*)d_out;               // [B]
  const int B = in_sizes[0] / 64;
  const int G = in_sizes[2];

  _Float16* Cf = (_Float16*)d_ws;                // 1 MB, fragment-ordered
  float2* cw = (float2*)(Cf + (size_t)G*64);     // 64 KB

  convert_C<<<(G*4)/256, 256, 0, stream>>>(C, W, Cf, cw, out, G, B);
  rbf_mfma<<<(B/256)*GP, 256, 0, stream>>>(X, Cf, cw, out);
}

// Round 21
// 44.017 us; speedup vs baseline: 1.3565x; 1.0313x over previous
//
#include <hip/hip_runtime.h>

// out[b] = sum_g exp(-(||x_b||^2+||c_g||^2-2 x_b.c_g)/2) * w[g]
// B=16384, G=8192, D=64 fp32.
// v21 = v20 + EXPONENT FOLDED INTO MFMA: A pre-scaled by log2(e) at f16
// conversion; MFMA C-operand initialized with the per-column cn splat
// (C/D col = lane&31 -> cn per-lane uniform). Acc exits MFMA = L2E*dot+cn;
// EPI element = exp2 + fma only (-32 VALU and -1 dep stage per tile/wave).
// cw prefetched one tile ahead (reuses TN; tail wraps to t0, value dead).
// History: v16 skeleton best (40.9us); SGB corrupts (v11); branches
// fragment (v17); poly-exp saturates VALU (v19); P/C waves race/spill.

typedef __attribute__((ext_vector_type(8))) _Float16 half8v;
typedef __attribute__((ext_vector_type(16))) float f32x16;
typedef unsigned short u16;
typedef unsigned int u32;

#define L2E   1.4426950408889634f
#define NHL2E 0.72134752044448170f   // log2(e)/2
#define GP 12                        // col parts: gp<4 -> 22 tiles, else 21

#define MFMA(a,b,c) __builtin_amdgcn_mfma_f32_32x32x16_f16(a,b,c,0,0,0)

// ---- one-time: C [G][64] fp32 -> f16 in MFMA fragment order + (cn,w);
// also zeroes out[] (32768 threads >= B; replaces the memset dispatch). ----
__global__ __launch_bounds__(256)
void convert_C(const float* __restrict__ C, const float* __restrict__ W,
               _Float16* __restrict__ Cf, float2* __restrict__ cw,
               float* __restrict__ out, int G, int B){
  int idx = blockIdx.x*256 + threadIdx.x;
  if (idx < B) out[idx] = 0.f;
  int g = idx >> 2, f = idx & 3;
  if (g >= G) return;
  const float* row = C + (size_t)g*64 + f*16;
  int cg = g >> 5, cl = g & 31;
  float norm = 0.f;
  _Float16 hv[16];
  #pragma unroll
  for (int q=0; q<4; q++){
    float4 v = *(const float4*)(row + q*4);
    float xv[4] = {v.x, v.y, v.z, v.w};
    #pragma unroll
    for (int e=0; e<4; e++){
      float x = xv[e];
      norm = fmaf(x, x, norm);
      hv[q*4+e] = (_Float16)x;       // RNE f32->f16 (B unscaled; A carries L2E)
    }
  }
  norm += __shfl_xor(norm, 1);       // reduce over the 4 f-lanes of this g
  norm += __shfl_xor(norm, 2);
  size_t u = ((size_t)(cg*4 + f)*64 + cl)*8;
  *(half8v*)(Cf + u)       = *(half8v*)hv;        // h=0 (k 0..7)
  *(half8v*)(Cf + u + 256) = *(half8v*)(hv + 8);  // h=1 (k 8..15)
  if (f == 0) cw[g] = make_float2(-NHL2E*norm, W[g]);
}

__global__ __launch_bounds__(256, 3)
void rbf_mfma(const float* __restrict__ X, const _Float16* __restrict__ Cf,
              const float2* __restrict__ cw, float* __restrict__ out){
  const int tid = threadIdx.x;
  const int l  = tid & 63;
  const int cl = l & 31;
  const int h  = l >> 5;
  const int w  = tid >> 6;
  const int b  = blockIdx.x;
  const int gp = b % GP;               // 4 waves share gp -> L1/L2 B-sharing
  const int rows0 = (b / GP) * 256 + w * 64;

  // global col-tile range for this part (256 tiles of 32 cols over G)
  const int t0  = gp * 21 + (gp < 4 ? gp : 4);
  const int ntl = (gp < 4) ? 22 : 21;

  // ---- A: 64 rows (2 rowfrags), PRE-SCALED by L2E, f16 in regs + norms ----
  half8v af[2][4];
  float xn[2];
  #pragma unroll
  for (int rf=0; rf<2; rf++){
    const float* xr = X + (size_t)(rows0 + rf*32 + cl)*64;
    float s = 0.f;
    #pragma unroll
    for (int f=0; f<4; f++){
      float4 v0 = *(const float4*)(xr + f*16 + h*8);
      float4 v1 = *(const float4*)(xr + f*16 + h*8 + 4);
      float xv[8] = {v0.x,v0.y,v0.z,v0.w,v1.x,v1.y,v1.z,v1.w};
      _Float16 hv[8];
      #pragma unroll
      for (int e=0;e<8;e++){
        float x = xv[e];
        s = fmaf(x, x, s);
        hv[e] = (_Float16)(x * L2E);   // scale folded into A
      }
      af[rf][f] = *(half8v*)hv;
    }
    s += __shfl_xor(s, 32);
    xn[rf] = -NHL2E * s;
  }

  // B stream: byte addr = T*4096 + f*1024 + l*16 (T = global col-tile)
  const char* baseF = (const char*)Cf + (size_t)l*16;
  const float2* cwp = cw + cl;

  half8v bf[2];
  bf[0] = *(const half8v*)(baseF + (size_t)t0*4096);   // (t0, f=0)

  float racc0[16], racc1[16];
  #pragma unroll
  for (int r=0;r<16;r++){ racc0[r]=0.f; racc1[r]=0.f; }

  f32x16 aE0, aE1, aO0, aO1;
  float2 cwE, cwO;

  // one epilogue element: acc already holds L2E*dot + cn
  #define EPIX(P, R, CWV, RACC)                                             \
    RACC[R] = fmaf(__builtin_amdgcn_exp2f(P[R]), CWV.y, RACC[R])

  // tile T: C-init from CWC.x (cn splat), 8 MFMA, EPI of prev tile (CWP.y)
  // interleaved; B prefetch toward TN; at end reload CWP <- cw(TN) (next
  // tile's cw; for the final tile TN=t0, value dead).
  #define TILE(T, TN, C0, C1, P0, P1, CWC, CWP, DO_EPI) do {                \
    const int t_ = (T), tn_ = (TN);                                         \
    _Pragma("unroll")                                                       \
    for (int r=0;r<16;++r){ C0[r] = CWC.x; C1[r] = CWC.x; }                 \
    _Pragma("unroll")                                                       \
    for (int f=0; f<4; ++f){                                                \
      const int p = f & 1, q = p ^ 1;                                       \
      const int nf = (f + 1) & 3;                                           \
      const int nt = (f == 3) ? tn_ : t_;                                   \
      bf[q] = *(const half8v*)(baseF + (size_t)nt*4096 + (size_t)nf*1024);  \
      C0 = MFMA(af[0][f], bf[p], C0);                                       \
      if (DO_EPI){                                                          \
        EPIX(P0, f*4+0, CWP, racc0); EPIX(P1, f*4+0, CWP, racc1);           \
        EPIX(P0, f*4+1, CWP, racc0); EPIX(P1, f*4+1, CWP, racc1);           \
      }                                                                     \
      C1 = MFMA(af[1][f], bf[p], C1);                                       \
      if (DO_EPI){                                                          \
        EPIX(P0, f*4+2, CWP, racc0); EPIX(P1, f*4+2, CWP, racc1);           \
        EPIX(P0, f*4+3, CWP, racc0); EPIX(P1, f*4+3, CWP, racc1);           \
      }                                                                     \
    }                                                                       \
    CWP = cwp[tn_*32];                 /* prefetch next tile's (cn,w) */    \
  } while(0)

  // prologue: load cw(t0); tile t0 (even slot), no EPI; end-load cwO=cw(t0+1)
  cwE = cwp[t0*32];
  TILE(t0, t0+1, aE0, aE1, aO0, aO1, cwE, cwO, 0);
  int ti = 1;
  #pragma unroll 1
  for (; ti + 1 < ntl; ti += 2){
    const int To = t0 + ti, Te = t0 + ti + 1;
    const int TnO = Te;                            // next after odd tile
    const int TnE = (ti + 2 < ntl) ? Te + 1 : t0;  // wrap: value dead
    TILE(To, TnO, aO0, aO1, aE0, aE1, cwO, cwE, 1);
    TILE(Te, TnE, aE0, aE1, aO0, aO1, cwE, cwO, 1);
  }
  if (ti < ntl){
    // ntl even: one final odd tile, then flush both
    TILE(t0+ti, t0, aO0, aO1, aE0, aE1, cwO, cwE, 1);
    #pragma unroll
    for (int r=0;r<16;++r){ EPIX(aO0, r, cwO, racc0); EPIX(aO1, r, cwO, racc1); }
  } else {
    // ntl odd: flush the last even tile
    #pragma unroll
    for (int r=0;r<16;++r){ EPIX(aE0, r, cwE, racc0); EPIX(aE1, r, cwE, racc1); }
  }
  #undef TILE
  #undef EPIX

  // ---- reduce over 32 col-lanes, fold 2^xn, one atomic per row ----
  #pragma unroll
  for (int rf=0; rf<2; rf++){
    #pragma unroll
    for (int r=0;r<16;r++){
      float v = rf ? racc1[r] : racc0[r];
      v += __shfl_xor(v, 1);
      v += __shfl_xor(v, 2);
      v += __shfl_xor(v, 4);
      v += __shfl_xor(v, 8);
      v += __shfl_xor(v, 16);
      const int rit = (r&3) + 8*(r>>2) + 4*h;
      const float xnv = __shfl(xn[rf], rit);
      if (cl == 0)
        atomicAdd(&out[rows0 + rf*32 + rit], v * __builtin_amdgcn_exp2f(xnv));
    }
  }
}

extern "C" void kernel_launch(void* const* d_in, const int* in_sizes, int n_in,
                              void* d_out, int out_size, void* d_ws, size_t ws_size,
                              hipStream_t stream) {
  const float* X = (const float*)d_in[0];   // [B,64]
  const float* C = (const float*)d_in[1];   // [G,64]
  const float* W = (const float*)d_in[2];   // [G]
  float* out = (float*)d_out;               // [B]
  const int B = in_sizes[0] / 64;
  const int G = in_sizes[2];

  _Float16* Cf = (_Float16*)d_ws;                // 1 MB, fragment-ordered
  float2* cw = (float2*)(Cf + (size_t)G*64);     // 64 KB

  convert_C<<<(G*4)/256, 256, 0, stream>>>(C, W, Cf, cw, out, G, B);
  rbf_mfma<<<(B/256)*GP, 256, 0, stream>>>(X, Cf, cw, out);
}